// Round 2
// baseline (2813.035 us; speedup 1.0000x reference)
//
#include <hip/hip_runtime.h>

#define ALPHA_C 0.05f
#define BETA_C  0.95f
#define GAMMA_C 0.95f

constexpr int B = 16, T = 24, N = 512, F = 2, H = 64, E = 16;
constexpr int DA = 8;        // D_ATTN
constexpr int CC = F + H;    // 66
constexpr int TGN_OC = 32;

__device__ __forceinline__ float fast_tanh(float x) {
    return 1.0f - 2.0f / (__expf(2.0f * x) + 1.0f);
}
__device__ __forceinline__ float fast_sigmoid(float x) {
    return 1.0f / (1.0f + __expf(-x));
}

// ---------------------------------------------------------------------------
// bmm2: out[b,w,c] = ALPHA*x[b,w,c] + sum_v M[v,w]*h[b,v,c]
//   M[v,w] = GAMMA*A[v,w] (+ BETA*adp[b,v,w] if TWOM) -- combined at stage time.
// C = 64+GCOLS (GCOLS=0 or 2). WT=64, VT=64, block 256 = 16 cg x 16 wg,
// each thread: 4 rows (4*wg..) x 4 contiguous cols (4*cg..); cols 64,65
// handled by exec-masked cg<2 lanes. All compute-phase LDS reads are b128.
// Grid: (N/64, B) = 128 blocks.
// ---------------------------------------------------------------------------
template<bool TWOM, int GCOLS>
__global__ __launch_bounds__(256) void bmm2_kernel(
    float* __restrict__ out, const float* __restrict__ x, const float* __restrict__ h,
    const float* __restrict__ MA, const float* __restrict__ MB)
{
    constexpr int Crow = 64 + GCOLS;
    __shared__ float sh_m[64][68];
    __shared__ float sh_h[64][68];

    const int b  = blockIdx.y;
    const int w0 = blockIdx.x * 64;
    const int tid = threadIdx.x;
    const int cg = tid & 15;    // col group: cols 4cg..4cg+3
    const int wg = tid >> 4;    // row group: rows 4wg..4wg+3

    float acc[4][4];
#pragma unroll
    for (int r = 0; r < 4; ++r)
#pragma unroll
        for (int c = 0; c < 4; ++c) acc[r][c] = 0.0f;
    float ag[4] = {0.f, 0.f, 0.f, 0.f};   // G-col accum (cg<GCOLS lanes)

    const float* Mb = TWOM ? (MB + (size_t)b * N * N) : nullptr;
    const float* hb = h + (size_t)b * N * Crow;

    for (int vt = 0; vt < 8; ++vt) {
        const int v0 = vt * 64;
        // ---- stage M (combined) ----
#pragma unroll
        for (int it = 0; it < 4; ++it) {
            int l = it * 256 + tid;
            int row = l >> 4;           // v within tile
            int c4 = (l & 15) << 2;     // w within tile
            const float4 av = *(const float4*)(MA + (size_t)(v0 + row) * N + w0 + c4);
            float4 val;
            if (TWOM) {
                const float4 bv = *(const float4*)(Mb + (size_t)(v0 + row) * N + w0 + c4);
                val.x = GAMMA_C * av.x + BETA_C * bv.x;
                val.y = GAMMA_C * av.y + BETA_C * bv.y;
                val.z = GAMMA_C * av.z + BETA_C * bv.z;
                val.w = GAMMA_C * av.w + BETA_C * bv.w;
            } else {
                val.x = GAMMA_C * av.x; val.y = GAMMA_C * av.y;
                val.z = GAMMA_C * av.z; val.w = GAMMA_C * av.w;
            }
            *(float4*)&sh_m[row][c4] = val;
        }
        // ---- stage h tile ----
        if (GCOLS == 2) {
            const float2* hb2 = (const float2*)(hb + (size_t)v0 * Crow);
            for (int l = tid; l < 64 * 33; l += 256) {
                int row = l / 33;
                int k = l - row * 33;
                *(float2*)&sh_h[row][2 * k] = hb2[l];
            }
        } else {
            const float4* hb4 = (const float4*)(hb + (size_t)v0 * Crow);
#pragma unroll
            for (int it = 0; it < 4; ++it) {
                int l = it * 256 + tid;
                int row = l >> 4;
                int k = (l & 15) << 2;
                *(float4*)&sh_h[row][k] = hb4[l];
            }
        }
        __syncthreads();
        // ---- compute ----
#pragma unroll 8
        for (int j = 0; j < 64; ++j) {
            float4 mv = *(const float4*)&sh_m[j][wg << 2];
            float4 hv = *(const float4*)&sh_h[j][cg << 2];
            acc[0][0] += mv.x * hv.x; acc[0][1] += mv.x * hv.y; acc[0][2] += mv.x * hv.z; acc[0][3] += mv.x * hv.w;
            acc[1][0] += mv.y * hv.x; acc[1][1] += mv.y * hv.y; acc[1][2] += mv.y * hv.z; acc[1][3] += mv.y * hv.w;
            acc[2][0] += mv.z * hv.x; acc[2][1] += mv.z * hv.y; acc[2][2] += mv.z * hv.z; acc[2][3] += mv.z * hv.w;
            acc[3][0] += mv.w * hv.x; acc[3][1] += mv.w * hv.y; acc[3][2] += mv.w * hv.z; acc[3][3] += mv.w * hv.w;
            if (GCOLS > 0 && cg < GCOLS) {
                float gv = sh_h[j][64 + cg];
                ag[0] += mv.x * gv; ag[1] += mv.y * gv; ag[2] += mv.z * gv; ag[3] += mv.w * gv;
            }
        }
        __syncthreads();
    }
    // ---- epilogue ----
#pragma unroll
    for (int r = 0; r < 4; ++r) {
        const int w = w0 + (wg << 2) + r;
        const size_t base = ((size_t)b * N + w) * Crow + (cg << 2);
        if (GCOLS == 2) {
            float2 x01 = *(const float2*)(x + base);
            float2 x23 = *(const float2*)(x + base + 2);
            float2 o01, o23;
            o01.x = ALPHA_C * x01.x + acc[r][0];
            o01.y = ALPHA_C * x01.y + acc[r][1];
            o23.x = ALPHA_C * x23.x + acc[r][2];
            o23.y = ALPHA_C * x23.y + acc[r][3];
            *(float2*)(out + base) = o01;
            *(float2*)(out + base + 2) = o23;
            if (cg < GCOLS) {
                size_t gb = ((size_t)b * N + w) * Crow + 64 + cg;
                out[gb] = ALPHA_C * x[gb] + ag[r];
            }
        } else {
            float4 xv = *(const float4*)(x + base);
            float4 ov;
            ov.x = ALPHA_C * xv.x + acc[r][0];
            ov.y = ALPHA_C * xv.y + acc[r][1];
            ov.z = ALPHA_C * xv.z + acc[r][2];
            ov.w = ALPHA_C * xv.w + acc[r][3];
            *(float4*)(out + base) = ov;
        }
    }
}

// ---------------------------------------------------------------------------
// gsgt2: block handles 64 rows; stages hidden/hh1/hh2 (64x192) in LDS.
// tid: e = tid&15, rg = tid>>4 -> 4 rows each. Grid 128 blocks.
// ---------------------------------------------------------------------------
__global__ __launch_bounds__(256) void gsgt2_kernel(
    const float* __restrict__ hidden, const float* __restrict__ hh1, const float* __restrict__ hh2,
    const float* __restrict__ Wa1, const float* __restrict__ ba1,
    const float* __restrict__ Wa2, const float* __restrict__ ba2,
    const float* __restrict__ graph, long gstride,
    const float* __restrict__ Wsrc, const float* __restrict__ bsrc,
    const float* __restrict__ Wtgt, const float* __restrict__ btgt,
    float* __restrict__ nv_s, float* __restrict__ nv_t)
{
    __shared__ float sh[64][196];
    const int tid = threadIdx.x;
    const int e = tid & 15;
    const int rg = tid >> 4;
    const size_t nn0 = (size_t)blockIdx.x * 64;
    const float* segs[3] = {hidden, hh1, hh2};
#pragma unroll
    for (int s = 0; s < 3; ++s) {
        const float4* sp = (const float4*)(segs[s] + nn0 * 64);
#pragma unroll
        for (int it = 0; it < 4; ++it) {
            int l = it * 256 + tid;
            int row = l >> 4;
            int k = (l & 15) << 2;
            *(float4*)&sh[row][s * 64 + k] = sp[l];
        }
    }
    __syncthreads();
    float gs[4], gt[4];
#pragma unroll
    for (int r = 0; r < 4; ++r) { gs[r] = ba1[e]; gt[r] = ba2[e]; }
#pragma unroll 2
    for (int sk = 0; sk < 192; ++sk) {
        float w1 = Wa1[(size_t)sk * E + e];
        float w2 = Wa2[(size_t)sk * E + e];
#pragma unroll
        for (int r = 0; r < 4; ++r) {
            float v = sh[rg * 4 + r][sk];
            gs[r] += v * w1;
            gt[r] += v * w2;
        }
    }
#pragma unroll
    for (int r = 0; r < 4; ++r) {
        size_t nn = nn0 + rg * 4 + r;
        int b = (int)(nn >> 9), n = (int)(nn & (N - 1));
        const float* g = graph + (size_t)b * gstride + (size_t)n * F;
        float g0 = g[0], g1 = g[1];
        float es = g0 * Wsrc[e] + g1 * Wsrc[E + e] + bsrc[e];
        float et = g0 * Wtgt[e] + g1 * Wtgt[E + e] + btgt[e];
        nv_s[nn * E + e] = fast_tanh(2.0f * es * gs[r]);
        nv_t[nn * E + e] = fast_tanh(2.0f * et * gt[r]);
    }
}

// ---------------------------------------------------------------------------
// adp2: 4 rows per block (512 threads, one m per thread). float4 loads.
// ---------------------------------------------------------------------------
__global__ __launch_bounds__(512) void adp2_kernel(
    const float* __restrict__ nv_s, const float* __restrict__ nv_t, float* __restrict__ adp)
{
    __shared__ float red[8][4];
    __shared__ float tot[4];
    const int m = threadIdx.x;
    const int n0 = blockIdx.x * 4;
    const int b = blockIdx.y;
    const float4* sm = (const float4*)(nv_s + ((size_t)b * N + m) * E);
    const float4* tm = (const float4*)(nv_t + ((size_t)b * N + m) * E);
    const float4* sn = (const float4*)(nv_s + ((size_t)b * N + n0) * E);
    const float4* tn = (const float4*)(nv_t + ((size_t)b * N + n0) * E);
    float a1[4] = {0.f,0.f,0.f,0.f}, a2[4] = {0.f,0.f,0.f,0.f};
#pragma unroll
    for (int dd = 0; dd < 4; ++dd) {
        float4 smv = sm[dd], tmv = tm[dd];
#pragma unroll
        for (int r = 0; r < 4; ++r) {
            float4 snv = sn[r * 4 + dd], tnv = tn[r * 4 + dd];
            a1[r] += snv.x * tmv.x + snv.y * tmv.y + snv.z * tmv.z + snv.w * tmv.w;
            a2[r] += tnv.x * smv.x + tnv.y * smv.y + tnv.z * smv.z + tnv.w * smv.w;
        }
    }
    float p[4];
#pragma unroll
    for (int r = 0; r < 4; ++r) {
        float pv = fast_tanh(2.0f * (a1[r] - a2[r]));
        pv = fmaxf(pv, 0.0f);
        if (m == n0 + r) pv += 1.0f;
        p[r] = pv;
    }
    float sr[4] = {p[0], p[1], p[2], p[3]};
    for (int o = 32; o > 0; o >>= 1) {
#pragma unroll
        for (int r = 0; r < 4; ++r) sr[r] += __shfl_down(sr[r], o);
    }
    int wid = m >> 6, lane = m & 63;
    if (lane == 0) {
#pragma unroll
        for (int r = 0; r < 4; ++r) red[wid][r] = sr[r];
    }
    __syncthreads();
    if (m < 4) {
        float t = 0.f;
        for (int i = 0; i < 8; ++i) t += red[i][m];
        tot[m] = t;
    }
    __syncthreads();
#pragma unroll
    for (int r = 0; r < 4; ++r)
        adp[((size_t)b * N + n0 + r) * N + m] = p[r] / tot[r];
}

// combined = concat([graph, hidden], -1)  -> (B,N,66)
__global__ void concat_kernel(const float* __restrict__ graph, long gstride,
                              const float* __restrict__ hidden, float* __restrict__ comb)
{
    int idx = blockIdx.x * 256 + threadIdx.x;   // B*N*CC
    int k = idx % CC;
    int nn = idx / CC;                           // b*N+n
    int n = nn & (N - 1);
    int b = nn >> 9;
    float v;
    if (k < F) v = graph[(size_t)b * gstride + (size_t)n * F + k];
    else       v = hidden[(size_t)nn * H + (k - F)];
    comb[idx] = v;
}

// ---------------------------------------------------------------------------
// zr2: block = 256 (oc = tid&63, rg = tid>>6, 8 rows each -> 32 rows/block).
// Stages comb/hr1/hr2 rows in LDS; W read once per 32 rows. Grid 256.
// ---------------------------------------------------------------------------
__global__ __launch_bounds__(256) void zr2_kernel(
    const float* __restrict__ comb, const float* __restrict__ hr1, const float* __restrict__ hr2,
    const float* __restrict__ Wgz, const float* __restrict__ bgz,
    const float* __restrict__ Wgr, const float* __restrict__ bgr,
    const float* __restrict__ hidden, const float* __restrict__ graph, long gstride,
    float* __restrict__ z, float* __restrict__ comb2)
{
    __shared__ float sh[32][200];
    const int tid = threadIdx.x;
    const int oc = tid & 63;
    const int rg = tid >> 6;
    const size_t nn0 = (size_t)blockIdx.x * 32;
    const float* segs[3] = {comb, hr1, hr2};
#pragma unroll
    for (int s = 0; s < 3; ++s) {
        const float2* sp = (const float2*)(segs[s] + nn0 * CC);
        for (int l = tid; l < 32 * 33; l += 256) {
            int row = l / 33;
            int k = l - row * 33;
            *(float2*)&sh[row][s * 66 + 2 * k] = sp[l];
        }
    }
    __syncthreads();
    float accz[8], accr[8];
#pragma unroll
    for (int rr = 0; rr < 8; ++rr) { accz[rr] = bgz[oc]; accr[rr] = bgr[oc]; }
#pragma unroll 2
    for (int sk = 0; sk < 198; ++sk) {
        float wz = Wgz[(size_t)sk * H + oc];
        float wr = Wgr[(size_t)sk * H + oc];
#pragma unroll
        for (int rr = 0; rr < 8; ++rr) {
            float v = sh[rg * 8 + rr][sk];
            accz[rr] += v * wz;
            accr[rr] += v * wr;
        }
    }
#pragma unroll
    for (int rr = 0; rr < 8; ++rr) {
        size_t nn = nn0 + rg * 8 + rr;
        float zv = fast_sigmoid(accz[rr]);
        float rv = fast_sigmoid(accr[rr]);
        z[nn * H + oc] = zv;
        comb2[nn * CC + F + oc] = rv * hidden[nn * H + oc];
        if (oc < F) {
            int b = (int)(nn >> 9), n = (int)(nn & (N - 1));
            comb2[nn * CC + oc] = graph[(size_t)b * gstride + (size_t)n * F + oc];
        }
    }
}

// c = tanh(cat @ W_gc + b); hidden = z*hidden + (1-z)*c. Same tiling as zr2.
__global__ __launch_bounds__(256) void c_update2_kernel(
    const float* __restrict__ comb2, const float* __restrict__ hc1, const float* __restrict__ hc2,
    const float* __restrict__ Wgc, const float* __restrict__ bgc,
    const float* __restrict__ z, float* __restrict__ hidden)
{
    __shared__ float sh[32][200];
    const int tid = threadIdx.x;
    const int oc = tid & 63;
    const int rg = tid >> 6;
    const size_t nn0 = (size_t)blockIdx.x * 32;
    const float* segs[3] = {comb2, hc1, hc2};
#pragma unroll
    for (int s = 0; s < 3; ++s) {
        const float2* sp = (const float2*)(segs[s] + nn0 * CC);
        for (int l = tid; l < 32 * 33; l += 256) {
            int row = l / 33;
            int k = l - row * 33;
            *(float2*)&sh[row][s * 66 + 2 * k] = sp[l];
        }
    }
    __syncthreads();
    float acc[8];
#pragma unroll
    for (int rr = 0; rr < 8; ++rr) acc[rr] = bgc[oc];
#pragma unroll 2
    for (int sk = 0; sk < 198; ++sk) {
        float wc = Wgc[(size_t)sk * H + oc];
#pragma unroll
        for (int rr = 0; rr < 8; ++rr) acc[rr] += sh[rg * 8 + rr][sk] * wc;
    }
#pragma unroll
    for (int rr = 0; rr < 8; ++rr) {
        size_t nn = nn0 + rg * 8 + rr;
        float cv = fast_tanh(acc[rr]);
        float zv = z[nn * H + oc];
        float ho = hidden[nn * H + oc];
        hidden[nn * H + oc] = zv * ho + (1.0f - zv) * cv;
    }
}

// q[b,n,d] = tar@w_query + bias; kk[b,t,n,d] = src@w_key
__global__ void qk_kernel(const float* __restrict__ sample,
                          const float* __restrict__ wq, const float* __restrict__ wk,
                          const float* __restrict__ attn_bias,
                          float* __restrict__ q, float* __restrict__ kk)
{
    int idx = blockIdx.x * 256 + threadIdx.x;
    if (idx < B * N * DA) {
        int d = idx & 7;
        int n = (idx >> 3) & (N - 1);
        int b = idx >> 12;
        const float* tar = sample + (((size_t)b * T + (T - 1)) * N + n) * F;
        q[idx] = tar[0] * wq[d] + tar[1] * wq[DA + d] + attn_bias[d];
    } else {
        int j = idx - B * N * DA;   // B*4*N*DA
        int d = j & 7;
        int n = (j >> 3) & (N - 1);
        int t = (j >> 12) & 3;
        int b = j >> 14;
        const float* s = sample + (((size_t)b * T + (T - 4 + t)) * N + n) * F;
        kk[j] = s[0] * wk[d] + s[1] * wk[DA + d];
    }
}

// scores + softmax over m; writes attn (B,4,N,N) into d_out
__global__ __launch_bounds__(512) void scores_kernel(
    const float* __restrict__ q, const float* __restrict__ kk,
    const float* __restrict__ trans, float* __restrict__ attn)
{
    __shared__ float red[8];
    int n = blockIdx.x, t = blockIdx.y, b = blockIdx.z, m = threadIdx.x;
    const float* qp = q + ((size_t)b * N + n) * DA;
    const float* kp = kk + (((size_t)(b * 4 + t)) * N + m) * DA;
    float s = 0.f;
#pragma unroll
    for (int d = 0; d < DA; ++d) s += fast_tanh(qp[d] + kp[d]) * trans[d];
    float mx = s;
    for (int o = 32; o > 0; o >>= 1) mx = fmaxf(mx, __shfl_down(mx, o));
    int wid = m >> 6, lane = m & 63;
    if (lane == 0) red[wid] = mx;
    __syncthreads();
    if (m == 0) { float r = red[0]; for (int i = 1; i < 8; ++i) r = fmaxf(r, red[i]); red[0] = r; }
    __syncthreads();
    mx = red[0];
    __syncthreads();
    float e = __expf(s - mx);
    float ss = e;
    for (int o = 32; o > 0; o >>= 1) ss += __shfl_down(ss, o);
    if (lane == 0) red[wid] = ss;
    __syncthreads();
    if (m == 0) { float r = 0.f; for (int i = 0; i < 8; ++i) r += red[i]; red[0] = r; }
    __syncthreads();
    attn[(((size_t)(b * 4 + t)) * N + n) * N + m] = e / red[0];
}

// TGN conv: out[bt,w,c] = 0.05*x + 0.95*sum_v (A[v,w]+attn[bt,v,w]) * h[bt,v,c]
__global__ __launch_bounds__(128) void tgn_mm_kernel(
    const float* __restrict__ A, const float* __restrict__ attn,
    const float* __restrict__ hbase, long hsB, long hsT,
    const float* __restrict__ xbase, long xsB, long xsT,
    float* __restrict__ out)
{
    __shared__ float sh_m[64][65];
    __shared__ float sh_h[64][2];
    int bt = blockIdx.y;
    int w0 = blockIdx.x * 64;
    int tid = threadIdx.x;
    int wl = tid >> 1, c = tid & 1;
    const float* hp = hbase + (size_t)(bt >> 2) * hsB + (size_t)(bt & 3) * hsT;
    const float* ap = attn + (size_t)bt * N * N;
    float acc = 0.f;
    for (int vt = 0; vt < 8; ++vt) {
        int v0 = vt * 64;
#pragma unroll
        for (int it = 0; it < 32; ++it) {
            int l = it * 128 + tid;
            int vr = l >> 6;
            int wc = l & 63;
            size_t gi = (size_t)(v0 + vr) * N + (w0 + wc);
            sh_m[wc][vr] = A[gi] + ap[gi];
        }
        {
            int r = tid >> 1, cc = tid & 1;
            sh_h[r][cc] = hp[(size_t)(v0 + r) * F + cc];
        }
        __syncthreads();
#pragma unroll 8
        for (int j = 0; j < 64; ++j) acc += sh_m[wl][j] * sh_h[j][c];
        __syncthreads();
    }
    const float* xp = xbase + (size_t)(bt >> 2) * xsB + (size_t)(bt & 3) * xsT;
    out[((size_t)bt * N + w0 + wl) * F + c] =
        ALPHA_C * xp[(size_t)(w0 + wl) * F + c] + GAMMA_C * acc;
}

// relu(cat @ W_tgn + b) summed over t -> tar32 (B,N,32)
__global__ void tgn_out_kernel(const float* __restrict__ sample,
                               const float* __restrict__ th1, const float* __restrict__ th2,
                               const float* __restrict__ Wt, const float* __restrict__ bt_,
                               float* __restrict__ tar32)
{
    int idx = blockIdx.x * 256 + threadIdx.x;  // B*N*32
    int oc = idx & 31;
    int n = (idx >> 5) & (N - 1);
    int b = idx >> 14;
    float acc = 0.f;
    for (int t = 0; t < 4; ++t) {
        int bt = b * 4 + t;
        const float* s = sample + (((size_t)b * T + (T - 4 + t)) * N + n) * F;
        size_t r = ((size_t)bt * N + n) * F;
        float v = bt_[oc];
        v += s[0] * Wt[0 * TGN_OC + oc] + s[1] * Wt[1 * TGN_OC + oc];
        v += th1[r] * Wt[2 * TGN_OC + oc] + th1[r + 1] * Wt[3 * TGN_OC + oc];
        v += th2[r] * Wt[4 * TGN_OC + oc] + th2[r + 1] * Wt[5 * TGN_OC + oc];
        acc += fmaxf(v, 0.0f);
    }
    tar32[idx] = acc;
}

__global__ void gat_kernel(const float* __restrict__ tar32,
                           const float* __restrict__ Ws, const float* __restrict__ bs,
                           float* __restrict__ out0)
{
    int idx = blockIdx.x * 256 + threadIdx.x;  // B*N*F
    int f = idx & 1;
    int nn = idx >> 1;
    float acc = bs[f];
    const float* tp = tar32 + (size_t)nn * TGN_OC;
    for (int k = 0; k < TGN_OC; ++k) acc += tp[k] * Ws[(size_t)k * F + f];
    out0[idx] = acc;
}

// gru_result + final_result
__global__ void final_kernel(const float* __restrict__ hidden, const float* __restrict__ tar32,
                             const float* __restrict__ Wl, const float* __restrict__ bl,
                             const float* __restrict__ Wm, const float* __restrict__ bm,
                             float* __restrict__ dout_gru, float* __restrict__ dout_fin)
{
    int idx = blockIdx.x * 256 + threadIdx.x;  // B*N*F
    int f = idx & 1;
    int nn = idx >> 1;
    const float* hp = hidden + (size_t)nn * H;
    const float* tp = tar32 + (size_t)nn * TGN_OC;
    float g = bl[f], fin = bm[f];
    for (int k = 0; k < H; ++k) g += hp[k] * Wl[(size_t)k * F + f];
    for (int k = 0; k < TGN_OC; ++k) fin += tp[k] * Wm[(size_t)k * F + f];
    for (int k = 0; k < H; ++k) fin += hp[k] * Wm[(size_t)(TGN_OC + k) * F + f];
    dout_gru[idx] = g;
    dout_fin[idx] = fin;
}

// ---------------------------------------------------------------------------
// Host side
// ---------------------------------------------------------------------------
namespace {
struct Ptrs {
    const float *sample, *A, *wq, *wk, *attn_bias, *attn_trans, *Wt, *bt_;
    const float *Wa1, *ba1, *Wa2, *ba2, *Wsrc, *bsrc, *Wtgt, *btgt;
    const float *Wgz, *bgz, *Wgr, *bgr, *Wgc, *bgc, *Wsh, *bsh, *Wl, *bl, *Wm, *bm;
    float *hidden, *hh1, *hh2, *nvs, *nvt, *adp, *comb, *hr1, *hr2, *z, *comb2;
    float *q, *kk, *th1, *th2, *tar32;
};

void gru_step(hipStream_t stream, const Ptrs& p, const float* graph, long gstride)
{
    dim3 bg(N / 64, B);   // 128 blocks
    bmm2_kernel<false, 0><<<bg, 256, 0, stream>>>(p.hh1, p.hidden, p.hidden, p.A, nullptr);
    bmm2_kernel<false, 0><<<bg, 256, 0, stream>>>(p.hh2, p.hidden, p.hh1, p.A, nullptr);
    gsgt2_kernel<<<B * N / 64, 256, 0, stream>>>(
        p.hidden, p.hh1, p.hh2, p.Wa1, p.ba1, p.Wa2, p.ba2, graph, gstride,
        p.Wsrc, p.bsrc, p.Wtgt, p.btgt, p.nvs, p.nvt);
    adp2_kernel<<<dim3(N / 4, B), 512, 0, stream>>>(p.nvs, p.nvt, p.adp);
    concat_kernel<<<(B * N * CC) / 256, 256, 0, stream>>>(graph, gstride, p.hidden, p.comb);
    bmm2_kernel<true, 2><<<bg, 256, 0, stream>>>(p.hr1, p.comb, p.comb, p.A, p.adp);
    bmm2_kernel<true, 2><<<bg, 256, 0, stream>>>(p.hr2, p.comb, p.hr1, p.A, p.adp);
    zr2_kernel<<<B * N / 32, 256, 0, stream>>>(
        p.comb, p.hr1, p.hr2, p.Wgz, p.bgz, p.Wgr, p.bgr, p.hidden, graph, gstride,
        p.z, p.comb2);
    bmm2_kernel<true, 2><<<bg, 256, 0, stream>>>(p.hr1, p.comb2, p.comb2, p.A, p.adp);
    bmm2_kernel<true, 2><<<bg, 256, 0, stream>>>(p.hr2, p.comb2, p.hr1, p.A, p.adp);
    c_update2_kernel<<<B * N / 32, 256, 0, stream>>>(
        p.comb2, p.hr1, p.hr2, p.Wgc, p.bgc, p.z, p.hidden);
}
}  // namespace

extern "C" void kernel_launch(void* const* d_in, const int* in_sizes, int n_in,
                              void* d_out, int out_size, void* d_ws, size_t ws_size,
                              hipStream_t stream)
{
    (void)in_sizes; (void)n_in; (void)out_size; (void)ws_size;
    Ptrs p;
    p.sample = (const float*)d_in[0];
    p.A      = (const float*)d_in[1];
    p.wq     = (const float*)d_in[2];
    p.wk     = (const float*)d_in[3];
    p.attn_bias  = (const float*)d_in[4];
    p.attn_trans = (const float*)d_in[5];
    p.Wt  = (const float*)d_in[6];
    p.bt_ = (const float*)d_in[7];
    p.Wa1 = (const float*)d_in[8];
    p.ba1 = (const float*)d_in[9];
    p.Wa2 = (const float*)d_in[10];
    p.ba2 = (const float*)d_in[11];
    p.Wsrc = (const float*)d_in[12];
    p.bsrc = (const float*)d_in[13];
    p.Wtgt = (const float*)d_in[14];
    p.btgt = (const float*)d_in[15];
    p.Wgz = (const float*)d_in[16];
    p.bgz = (const float*)d_in[17];
    p.Wgr = (const float*)d_in[18];
    p.bgr = (const float*)d_in[19];
    p.Wgc = (const float*)d_in[20];
    p.bgc = (const float*)d_in[21];
    p.Wsh = (const float*)d_in[22];
    p.bsh = (const float*)d_in[23];
    p.Wl  = (const float*)d_in[24];
    p.bl  = (const float*)d_in[25];
    p.Wm  = (const float*)d_in[26];
    p.bm  = (const float*)d_in[27];

    float* ws = (float*)d_ws;
    size_t off = 0;
    auto alloc = [&](size_t nelem) { float* r = ws + off; off += nelem; return r; };
    p.hidden = alloc((size_t)B * N * H);
    p.hh1    = alloc((size_t)B * N * H);
    p.hh2    = alloc((size_t)B * N * H);
    p.nvs    = alloc((size_t)B * N * E);
    p.nvt    = alloc((size_t)B * N * E);
    p.adp    = alloc((size_t)B * N * N);
    p.comb   = alloc((size_t)B * N * CC);
    p.hr1    = alloc((size_t)B * N * CC);
    p.hr2    = alloc((size_t)B * N * CC);
    p.z      = alloc((size_t)B * N * H);
    p.comb2  = alloc((size_t)B * N * CC);
    p.q      = alloc((size_t)B * N * DA);
    p.kk     = alloc((size_t)B * 4 * N * DA);
    p.th1    = alloc((size_t)B * 4 * N * F);
    p.th2    = alloc((size_t)B * 4 * N * F);
    p.tar32  = alloc((size_t)B * N * TGN_OC);

    float* out = (float*)d_out;
    float* out_gat = out;                      // (B,N,F)
    float* out_gru = out + (size_t)B * N * F;  // (B,N,F)
    float* out_fin = out + (size_t)2 * B * N * F;
    float* out_attn = out + (size_t)3 * B * N * F;  // (B,4,N,N)

    hipMemsetAsync(p.hidden, 0, (size_t)B * N * H * sizeof(float), stream);

    // 5 scan steps: graph_i = sample[:, 4*i]
    for (int i = 0; i < 5; ++i) {
        const float* graph = p.sample + (size_t)(4 * i) * N * F;
        gru_step(stream, p, graph, (long)T * N * F);
    }

    // attention + TGN
    qk_kernel<<<(B * N * DA + B * 4 * N * DA) / 256, 256, 0, stream>>>(
        p.sample, p.wq, p.wk, p.attn_bias, p.q, p.kk);
    scores_kernel<<<dim3(N, 4, B), 512, 0, stream>>>(p.q, p.kk, p.attn_trans, out_attn);

    const float* srcbase = p.sample + (size_t)(T - 4) * N * F;
    tgn_mm_kernel<<<dim3(N / 64, B * 4), 128, 0, stream>>>(
        p.A, out_attn, srcbase, (long)T * N * F, (long)N * F,
        srcbase, (long)T * N * F, (long)N * F, p.th1);
    tgn_mm_kernel<<<dim3(N / 64, B * 4), 128, 0, stream>>>(
        p.A, out_attn, p.th1, (long)4 * N * F, (long)N * F,
        srcbase, (long)T * N * F, (long)N * F, p.th2);
    tgn_out_kernel<<<(B * N * TGN_OC) / 256, 256, 0, stream>>>(
        p.sample, p.th1, p.th2, p.Wt, p.bt_, p.tar32);
    gat_kernel<<<(B * N * F) / 256, 256, 0, stream>>>(p.tar32, p.Wsh, p.bsh, out_gat);

    // final GRU step with graph = gat_result (contiguous in d_out)
    gru_step(stream, p, out_gat, (long)N * F);

    final_kernel<<<(B * N * F) / 256, 256, 0, stream>>>(
        p.hidden, p.tar32, p.Wl, p.bl, p.Wm, p.bm, out_gru, out_fin);
}

// Round 3
// 1961.633 us; speedup vs baseline: 1.4340x; 1.4340x over previous
//
#include <hip/hip_runtime.h>

#define ALPHA_C 0.05f
#define BETA_C  0.95f
#define GAMMA_C 0.95f

constexpr int B = 16, T = 24, N = 512, F = 2, H = 64, E = 16;
constexpr int DA = 8;        // D_ATTN
constexpr int CC = F + H;    // 66
constexpr int TGN_OC = 32;

__device__ __forceinline__ float fast_tanh(float x) {
    return 1.0f - 2.0f / (__expf(2.0f * x) + 1.0f);
}
__device__ __forceinline__ float fast_sigmoid(float x) {
    return 1.0f / (1.0f + __expf(-x));
}

// Ag = GAMMA * A  (once per launch)
__global__ void scaleA_kernel(const float* __restrict__ A, float* __restrict__ Ag)
{
    int i = blockIdx.x * 256 + threadIdx.x;
    Ag[i] = GAMMA_C * A[i];
}

// ---------------------------------------------------------------------------
// bmm3: out_part[vhalf][b,w,c] = (vhalf==0 ? ALPHA*x[b,w,c] : 0)
//                                + sum_{v in half} M[v,w]*in[b,v,c]
// M is pre-combined (Ag or Mcomb). in may itself be a partial pair (INSUM):
// in_total = in[l] + in[pstride + l].
// Grid (N/64, 2, B) = 256 blocks, 256 thr. 4x4 register tile (bmm2 core).
// ---------------------------------------------------------------------------
template<int GCOLS, bool INSUM, bool MPB>
__global__ __launch_bounds__(256) void bmm3_kernel(
    float* __restrict__ out, const float* __restrict__ x, const float* __restrict__ in,
    const float* __restrict__ M)
{
    constexpr int Crow = 64 + GCOLS;
    constexpr size_t pstride = (size_t)B * N * Crow;
    __shared__ float sh_m[64][68];
    __shared__ float sh_h[64][68];

    const int b  = blockIdx.z;
    const int vhalf = blockIdx.y;
    const int w0 = blockIdx.x * 64;
    const int tid = threadIdx.x;
    const int cg = tid & 15;    // cols 4cg..4cg+3
    const int wg = tid >> 4;    // rows 4wg..4wg+3

    float acc[4][4];
#pragma unroll
    for (int r = 0; r < 4; ++r)
#pragma unroll
        for (int c = 0; c < 4; ++c) acc[r][c] = 0.0f;
    float ag[4] = {0.f, 0.f, 0.f, 0.f};

    const float* Mbase = M + (MPB ? (size_t)b * N * N : 0);
    const float* inb   = in + (size_t)b * N * Crow;

    for (int vt = 0; vt < 4; ++vt) {
        const int v0 = vhalf * 256 + vt * 64;
        // stage M tile [v][w] (pre-combined, pure copy)
#pragma unroll
        for (int it = 0; it < 4; ++it) {
            int l = it * 256 + tid;
            int row = l >> 4;
            int c4 = (l & 15) << 2;
            *(float4*)&sh_m[row][c4] =
                *(const float4*)(Mbase + (size_t)(v0 + row) * N + w0 + c4);
        }
        // stage h tile (sum partials if INSUM)
        if (GCOLS == 2) {
            const float2* h0 = (const float2*)(inb + (size_t)v0 * Crow);
            const float2* h1 = INSUM ? (const float2*)(inb + pstride + (size_t)v0 * Crow) : nullptr;
            for (int l = tid; l < 64 * 33; l += 256) {
                int row = l / 33;
                int k = l - row * 33;
                float2 v = h0[l];
                if (INSUM) { float2 w = h1[l]; v.x += w.x; v.y += w.y; }
                *(float2*)&sh_h[row][2 * k] = v;
            }
        } else {
            const float4* h0 = (const float4*)(inb + (size_t)v0 * Crow);
            const float4* h1 = INSUM ? (const float4*)(inb + pstride + (size_t)v0 * Crow) : nullptr;
#pragma unroll
            for (int it = 0; it < 4; ++it) {
                int l = it * 256 + tid;
                int row = l >> 4;
                int k = (l & 15) << 2;
                float4 v = h0[l];
                if (INSUM) {
                    float4 w = h1[l];
                    v.x += w.x; v.y += w.y; v.z += w.z; v.w += w.w;
                }
                *(float4*)&sh_h[row][k] = v;
            }
        }
        __syncthreads();
#pragma unroll 8
        for (int j = 0; j < 64; ++j) {
            float4 mv = *(const float4*)&sh_m[j][wg << 2];
            float4 hv = *(const float4*)&sh_h[j][cg << 2];
            acc[0][0] += mv.x * hv.x; acc[0][1] += mv.x * hv.y; acc[0][2] += mv.x * hv.z; acc[0][3] += mv.x * hv.w;
            acc[1][0] += mv.y * hv.x; acc[1][1] += mv.y * hv.y; acc[1][2] += mv.y * hv.z; acc[1][3] += mv.y * hv.w;
            acc[2][0] += mv.z * hv.x; acc[2][1] += mv.z * hv.y; acc[2][2] += mv.z * hv.z; acc[2][3] += mv.z * hv.w;
            acc[3][0] += mv.w * hv.x; acc[3][1] += mv.w * hv.y; acc[3][2] += mv.w * hv.z; acc[3][3] += mv.w * hv.w;
            if (GCOLS > 0 && cg < GCOLS) {
                float gv = sh_h[j][64 + cg];
                ag[0] += mv.x * gv; ag[1] += mv.y * gv; ag[2] += mv.z * gv; ag[3] += mv.w * gv;
            }
        }
        __syncthreads();
    }
    // epilogue: vhalf0 adds ALPHA*x, vhalf1 stores raw partial
    float* outp = out + (size_t)vhalf * pstride + (size_t)b * N * Crow;
    const float* xb = x + (size_t)b * N * Crow;
#pragma unroll
    for (int r = 0; r < 4; ++r) {
        const int w = w0 + (wg << 2) + r;
        const size_t base = (size_t)w * Crow + (cg << 2);
        if (GCOLS == 2) {
            float o0 = acc[r][0], o1 = acc[r][1], o2 = acc[r][2], o3 = acc[r][3];
            if (vhalf == 0) {
                o0 += ALPHA_C * xb[base];
                o1 += ALPHA_C * xb[base + 1];
                o2 += ALPHA_C * xb[base + 2];
                o3 += ALPHA_C * xb[base + 3];
            }
            float2 a = {o0, o1}, bb = {o2, o3};
            *(float2*)(outp + base) = a;
            *(float2*)(outp + base + 2) = bb;
            if (cg < GCOLS) {
                size_t gb = (size_t)w * Crow + 64 + cg;
                float v = ag[r];
                if (vhalf == 0) v += ALPHA_C * xb[gb];
                outp[gb] = v;
            }
        } else {
            float4 ov = {acc[r][0], acc[r][1], acc[r][2], acc[r][3]};
            if (vhalf == 0) {
                float4 xv = *(const float4*)(xb + base);
                ov.x += ALPHA_C * xv.x; ov.y += ALPHA_C * xv.y;
                ov.z += ALPHA_C * xv.z; ov.w += ALPHA_C * xv.w;
            }
            *(float4*)(outp + base) = ov;
        }
    }
}

// ---------------------------------------------------------------------------
// gsgt3: 32 rows/block (grid 256). Stages hidden + (hh1 = P1 sum) + (hh2 = P2 sum).
// e = tid&15, rg = tid>>4 -> 2 rows each.
// ---------------------------------------------------------------------------
__global__ __launch_bounds__(256) void gsgt3_kernel(
    const float* __restrict__ hidden, const float* __restrict__ P1, const float* __restrict__ P2,
    const float* __restrict__ Wa1, const float* __restrict__ ba1,
    const float* __restrict__ Wa2, const float* __restrict__ ba2,
    const float* __restrict__ graph, long gstride,
    const float* __restrict__ Wsrc, const float* __restrict__ bsrc,
    const float* __restrict__ Wtgt, const float* __restrict__ btgt,
    float* __restrict__ nv_s, float* __restrict__ nv_t)
{
    constexpr size_t psH = (size_t)B * N * H;   // hyper partial stride
    __shared__ float sh[32][200];
    const int tid = threadIdx.x;
    const int e = tid & 15;
    const int rg = tid >> 4;
    const size_t nn0 = (size_t)blockIdx.x * 32;

    const float4* h4  = (const float4*)(hidden + nn0 * H);
    const float4* p1a = (const float4*)(P1 + nn0 * H);
    const float4* p1b = (const float4*)(P1 + psH + nn0 * H);
    const float4* p2a = (const float4*)(P2 + nn0 * H);
    const float4* p2b = (const float4*)(P2 + psH + nn0 * H);
#pragma unroll
    for (int it = 0; it < 2; ++it) {
        int l = it * 256 + tid;          // 512 float4 = 32 rows x 16
        int row = l >> 4;
        int k = (l & 15) << 2;
        float4 v0 = h4[l];
        *(float4*)&sh[row][k] = v0;
        float4 a = p1a[l], bb = p1b[l];
        a.x += bb.x; a.y += bb.y; a.z += bb.z; a.w += bb.w;
        *(float4*)&sh[row][64 + k] = a;
        float4 c = p2a[l], d = p2b[l];
        c.x += d.x; c.y += d.y; c.z += d.z; c.w += d.w;
        *(float4*)&sh[row][128 + k] = c;
    }
    __syncthreads();
    float gs[2], gt[2];
#pragma unroll
    for (int r = 0; r < 2; ++r) { gs[r] = ba1[e]; gt[r] = ba2[e]; }
#pragma unroll 4
    for (int sk = 0; sk < 192; ++sk) {
        float w1 = Wa1[(size_t)sk * E + e];
        float w2 = Wa2[(size_t)sk * E + e];
#pragma unroll
        for (int r = 0; r < 2; ++r) {
            float v = sh[rg * 2 + r][sk];
            gs[r] += v * w1;
            gt[r] += v * w2;
        }
    }
#pragma unroll
    for (int r = 0; r < 2; ++r) {
        size_t nn = nn0 + rg * 2 + r;
        int b = (int)(nn >> 9), n = (int)(nn & (N - 1));
        const float* g = graph + (size_t)b * gstride + (size_t)n * F;
        float g0 = g[0], g1 = g[1];
        float es = g0 * Wsrc[e] + g1 * Wsrc[E + e] + bsrc[e];
        float et = g0 * Wtgt[e] + g1 * Wtgt[E + e] + btgt[e];
        nv_s[nn * E + e] = fast_tanh(2.0f * es * gs[r]);
        nv_t[nn * E + e] = fast_tanh(2.0f * et * gt[r]);
    }
}

// ---------------------------------------------------------------------------
// adp3: 4 rows per block (grid (N/4, B) = 2048). Computes adp rows, writes
// Mcomb = GAMMA*A + BETA*adp, and materializes comb = [graph|hidden] rows.
// ---------------------------------------------------------------------------
__global__ __launch_bounds__(512) void adp3_kernel(
    const float* __restrict__ nv_s, const float* __restrict__ nv_t,
    const float* __restrict__ A,
    const float* __restrict__ hidden, const float* __restrict__ graph, long gstride,
    float* __restrict__ Mcomb, float* __restrict__ comb)
{
    __shared__ float red[8][4];
    __shared__ float tot[4];
    const int m = threadIdx.x;
    const int n0 = blockIdx.x * 4;
    const int b = blockIdx.y;
    const float4* sm = (const float4*)(nv_s + ((size_t)b * N + m) * E);
    const float4* tm = (const float4*)(nv_t + ((size_t)b * N + m) * E);
    const float4* sn = (const float4*)(nv_s + ((size_t)b * N + n0) * E);
    const float4* tn = (const float4*)(nv_t + ((size_t)b * N + n0) * E);
    float a1[4] = {0.f,0.f,0.f,0.f}, a2[4] = {0.f,0.f,0.f,0.f};
#pragma unroll
    for (int dd = 0; dd < 4; ++dd) {
        float4 smv = sm[dd], tmv = tm[dd];
#pragma unroll
        for (int r = 0; r < 4; ++r) {
            float4 snv = sn[r * 4 + dd], tnv = tn[r * 4 + dd];
            a1[r] += snv.x * tmv.x + snv.y * tmv.y + snv.z * tmv.z + snv.w * tmv.w;
            a2[r] += tnv.x * smv.x + tnv.y * smv.y + tnv.z * smv.z + tnv.w * smv.w;
        }
    }
    float p[4];
#pragma unroll
    for (int r = 0; r < 4; ++r) {
        float pv = fast_tanh(2.0f * (a1[r] - a2[r]));
        pv = fmaxf(pv, 0.0f);
        if (m == n0 + r) pv += 1.0f;
        p[r] = pv;
    }
    float sr[4] = {p[0], p[1], p[2], p[3]};
    for (int o = 32; o > 0; o >>= 1) {
#pragma unroll
        for (int r = 0; r < 4; ++r) sr[r] += __shfl_down(sr[r], o);
    }
    int wid = m >> 6, lane = m & 63;
    if (lane == 0) {
#pragma unroll
        for (int r = 0; r < 4; ++r) red[wid][r] = sr[r];
    }
    __syncthreads();
    if (m < 4) {
        float t = 0.f;
        for (int i = 0; i < 8; ++i) t += red[i][m];
        tot[m] = t;
    }
    __syncthreads();
#pragma unroll
    for (int r = 0; r < 4; ++r) {
        float inv = BETA_C / tot[r];
        Mcomb[((size_t)b * N + n0 + r) * N + m] =
            GAMMA_C * A[(size_t)(n0 + r) * N + m] + p[r] * inv;
    }
    // materialize comb rows n0..n0+3 (4 x 66 = 264 elements)
    if (m < 4 * CC) {
        int r = m / CC, k = m - r * CC;
        size_t nn = (size_t)b * N + n0 + r;
        float v;
        if (k < F) v = graph[(size_t)b * gstride + (size_t)(n0 + r) * F + k];
        else       v = hidden[nn * H + (k - F)];
        comb[nn * CC + k] = v;
    }
}

// ---------------------------------------------------------------------------
// zr3: 16 rows/block (grid 512). Stages comb + hr1(P1 sum) + hr2(P2 sum).
// oc = tid&63, rg = tid>>6 -> 4 rows. Writes z and comb2.
// ---------------------------------------------------------------------------
__global__ __launch_bounds__(256) void zr3_kernel(
    const float* __restrict__ comb, const float* __restrict__ P1, const float* __restrict__ P2,
    const float* __restrict__ Wgz, const float* __restrict__ bgz,
    const float* __restrict__ Wgr, const float* __restrict__ bgr,
    const float* __restrict__ hidden,
    float* __restrict__ z, float* __restrict__ comb2)
{
    constexpr size_t psC = (size_t)B * N * CC;
    __shared__ float sh[16][200];
    const int tid = threadIdx.x;
    const int oc = tid & 63;
    const int rg = tid >> 6;
    const size_t nn0 = (size_t)blockIdx.x * 16;

    const float2* c2  = (const float2*)(comb + nn0 * CC);
    const float2* p1a = (const float2*)(P1 + nn0 * CC);
    const float2* p1b = (const float2*)(P1 + psC + nn0 * CC);
    const float2* p2a = (const float2*)(P2 + nn0 * CC);
    const float2* p2b = (const float2*)(P2 + psC + nn0 * CC);
    for (int l = tid; l < 16 * 33; l += 256) {
        int row = l / 33;
        int k = (l - row * 33) * 2;
        float2 v = c2[l];
        *(float2*)&sh[row][k] = v;
        float2 a = p1a[l], bb = p1b[l];
        a.x += bb.x; a.y += bb.y;
        *(float2*)&sh[row][66 + k] = a;
        float2 c = p2a[l], d = p2b[l];
        c.x += d.x; c.y += d.y;
        *(float2*)&sh[row][132 + k] = c;
    }
    __syncthreads();
    float accz[4], accr[4];
#pragma unroll
    for (int rr = 0; rr < 4; ++rr) { accz[rr] = bgz[oc]; accr[rr] = bgr[oc]; }
#pragma unroll 2
    for (int sk = 0; sk < 198; ++sk) {
        float wz = Wgz[(size_t)sk * H + oc];
        float wr = Wgr[(size_t)sk * H + oc];
#pragma unroll
        for (int rr = 0; rr < 4; ++rr) {
            float v = sh[rg * 4 + rr][sk];
            accz[rr] += v * wz;
            accr[rr] += v * wr;
        }
    }
#pragma unroll
    for (int rr = 0; rr < 4; ++rr) {
        int row = rg * 4 + rr;
        size_t nn = nn0 + row;
        float zv = fast_sigmoid(accz[rr]);
        float rv = fast_sigmoid(accr[rr]);
        z[nn * H + oc] = zv;
        comb2[nn * CC + F + oc] = rv * hidden[nn * H + oc];
        if (oc < F) comb2[nn * CC + oc] = sh[row][oc];   // graph cols from comb
    }
}

// cup3: same tiling; c = tanh(...), hidden = z*h + (1-z)*c
__global__ __launch_bounds__(256) void cup3_kernel(
    const float* __restrict__ comb2, const float* __restrict__ P1, const float* __restrict__ P2,
    const float* __restrict__ Wgc, const float* __restrict__ bgc,
    const float* __restrict__ z, float* __restrict__ hidden)
{
    constexpr size_t psC = (size_t)B * N * CC;
    __shared__ float sh[16][200];
    const int tid = threadIdx.x;
    const int oc = tid & 63;
    const int rg = tid >> 6;
    const size_t nn0 = (size_t)blockIdx.x * 16;

    const float2* c2  = (const float2*)(comb2 + nn0 * CC);
    const float2* p1a = (const float2*)(P1 + nn0 * CC);
    const float2* p1b = (const float2*)(P1 + psC + nn0 * CC);
    const float2* p2a = (const float2*)(P2 + nn0 * CC);
    const float2* p2b = (const float2*)(P2 + psC + nn0 * CC);
    for (int l = tid; l < 16 * 33; l += 256) {
        int row = l / 33;
        int k = (l - row * 33) * 2;
        float2 v = c2[l];
        *(float2*)&sh[row][k] = v;
        float2 a = p1a[l], bb = p1b[l];
        a.x += bb.x; a.y += bb.y;
        *(float2*)&sh[row][66 + k] = a;
        float2 c = p2a[l], d = p2b[l];
        c.x += d.x; c.y += d.y;
        *(float2*)&sh[row][132 + k] = c;
    }
    __syncthreads();
    float acc[4];
#pragma unroll
    for (int rr = 0; rr < 4; ++rr) acc[rr] = bgc[oc];
#pragma unroll 2
    for (int sk = 0; sk < 198; ++sk) {
        float wc = Wgc[(size_t)sk * H + oc];
#pragma unroll
        for (int rr = 0; rr < 4; ++rr) acc[rr] += sh[rg * 4 + rr][sk] * wc;
    }
#pragma unroll
    for (int rr = 0; rr < 4; ++rr) {
        size_t nn = nn0 + rg * 4 + rr;
        float cv = fast_tanh(acc[rr]);
        float zv = z[nn * H + oc];
        float ho = hidden[nn * H + oc];
        hidden[nn * H + oc] = zv * ho + (1.0f - zv) * cv;
    }
}

// q[b,n,d] = tar@w_query + bias; kk[b,t,n,d] = src@w_key
__global__ void qk_kernel(const float* __restrict__ sample,
                          const float* __restrict__ wq, const float* __restrict__ wk,
                          const float* __restrict__ attn_bias,
                          float* __restrict__ q, float* __restrict__ kk)
{
    int idx = blockIdx.x * 256 + threadIdx.x;
    if (idx < B * N * DA) {
        int d = idx & 7;
        int n = (idx >> 3) & (N - 1);
        int b = idx >> 12;
        const float* tar = sample + (((size_t)b * T + (T - 1)) * N + n) * F;
        q[idx] = tar[0] * wq[d] + tar[1] * wq[DA + d] + attn_bias[d];
    } else {
        int j = idx - B * N * DA;
        int d = j & 7;
        int n = (j >> 3) & (N - 1);
        int t = (j >> 12) & 3;
        int b = j >> 14;
        const float* s = sample + (((size_t)b * T + (T - 4 + t)) * N + n) * F;
        kk[j] = s[0] * wk[d] + s[1] * wk[DA + d];
    }
}

// scores + softmax over m (no max pass: |s| <= sum|trans| ~ small)
__global__ __launch_bounds__(512) void scores_kernel(
    const float* __restrict__ q, const float* __restrict__ kk,
    const float* __restrict__ trans, float* __restrict__ attn)
{
    __shared__ float red[8];
    int n = blockIdx.x, t = blockIdx.y, b = blockIdx.z, m = threadIdx.x;
    const float* qp = q + ((size_t)b * N + n) * DA;
    const float* kp = kk + (((size_t)(b * 4 + t)) * N + m) * DA;
    float s = 0.f;
#pragma unroll
    for (int d = 0; d < DA; ++d) s += fast_tanh(qp[d] + kp[d]) * trans[d];
    float e = __expf(s);
    float ss = e;
    for (int o = 32; o > 0; o >>= 1) ss += __shfl_down(ss, o);
    int wid = m >> 6, lane = m & 63;
    if (lane == 0) red[wid] = ss;
    __syncthreads();
    if (m == 0) { float r = 0.f; for (int i = 0; i < 8; ++i) r += red[i]; red[0] = r; }
    __syncthreads();
    attn[(((size_t)(b * 4 + t)) * N + n) * N + m] = e / red[0];
}

// TGN conv: out[bt,w,c] = 0.05*x + 0.95*sum_v (A[v,w]+attn[bt,v,w]) * h[bt,v,c]
__global__ __launch_bounds__(128) void tgn_mm_kernel(
    const float* __restrict__ A, const float* __restrict__ attn,
    const float* __restrict__ hbase, long hsB, long hsT,
    const float* __restrict__ xbase, long xsB, long xsT,
    float* __restrict__ out)
{
    __shared__ float sh_m[64][65];
    __shared__ float sh_h[64][2];
    int bt = blockIdx.y;
    int w0 = blockIdx.x * 64;
    int tid = threadIdx.x;
    int wl = tid >> 1, c = tid & 1;
    const float* hp = hbase + (size_t)(bt >> 2) * hsB + (size_t)(bt & 3) * hsT;
    const float* ap = attn + (size_t)bt * N * N;
    float acc = 0.f;
    for (int vt = 0; vt < 8; ++vt) {
        int v0 = vt * 64;
#pragma unroll
        for (int it = 0; it < 32; ++it) {
            int l = it * 128 + tid;
            int vr = l >> 6;
            int wc = l & 63;
            size_t gi = (size_t)(v0 + vr) * N + (w0 + wc);
            sh_m[wc][vr] = A[gi] + ap[gi];
        }
        {
            int r = tid >> 1, cc = tid & 1;
            sh_h[r][cc] = hp[(size_t)(v0 + r) * F + cc];
        }
        __syncthreads();
#pragma unroll 8
        for (int j = 0; j < 64; ++j) acc += sh_m[wl][j] * sh_h[j][c];
        __syncthreads();
    }
    const float* xp = xbase + (size_t)(bt >> 2) * xsB + (size_t)(bt & 3) * xsT;
    out[((size_t)bt * N + w0 + wl) * F + c] =
        ALPHA_C * xp[(size_t)(w0 + wl) * F + c] + GAMMA_C * acc;
}

// relu(cat @ W_tgn + b) summed over t -> tar32 (B,N,32)
__global__ void tgn_out_kernel(const float* __restrict__ sample,
                               const float* __restrict__ th1, const float* __restrict__ th2,
                               const float* __restrict__ Wt, const float* __restrict__ bt_,
                               float* __restrict__ tar32)
{
    int idx = blockIdx.x * 256 + threadIdx.x;
    int oc = idx & 31;
    int n = (idx >> 5) & (N - 1);
    int b = idx >> 14;
    float acc = 0.f;
    for (int t = 0; t < 4; ++t) {
        int bt = b * 4 + t;
        const float* s = sample + (((size_t)b * T + (T - 4 + t)) * N + n) * F;
        size_t r = ((size_t)bt * N + n) * F;
        float v = bt_[oc];
        v += s[0] * Wt[0 * TGN_OC + oc] + s[1] * Wt[1 * TGN_OC + oc];
        v += th1[r] * Wt[2 * TGN_OC + oc] + th1[r + 1] * Wt[3 * TGN_OC + oc];
        v += th2[r] * Wt[4 * TGN_OC + oc] + th2[r + 1] * Wt[5 * TGN_OC + oc];
        acc += fmaxf(v, 0.0f);
    }
    tar32[idx] = acc;
}

__global__ void gat_kernel(const float* __restrict__ tar32,
                           const float* __restrict__ Ws, const float* __restrict__ bs,
                           float* __restrict__ out0)
{
    int idx = blockIdx.x * 256 + threadIdx.x;
    int f = idx & 1;
    int nn = idx >> 1;
    float acc = bs[f];
    const float* tp = tar32 + (size_t)nn * TGN_OC;
    for (int k = 0; k < TGN_OC; ++k) acc += tp[k] * Ws[(size_t)k * F + f];
    out0[idx] = acc;
}

__global__ void final_kernel(const float* __restrict__ hidden, const float* __restrict__ tar32,
                             const float* __restrict__ Wl, const float* __restrict__ bl,
                             const float* __restrict__ Wm, const float* __restrict__ bm,
                             float* __restrict__ dout_gru, float* __restrict__ dout_fin)
{
    int idx = blockIdx.x * 256 + threadIdx.x;
    int f = idx & 1;
    int nn = idx >> 1;
    const float* hp = hidden + (size_t)nn * H;
    const float* tp = tar32 + (size_t)nn * TGN_OC;
    float g = bl[f], fin = bm[f];
    for (int k = 0; k < H; ++k) g += hp[k] * Wl[(size_t)k * F + f];
    for (int k = 0; k < TGN_OC; ++k) fin += tp[k] * Wm[(size_t)k * F + f];
    for (int k = 0; k < H; ++k) fin += hp[k] * Wm[(size_t)(TGN_OC + k) * F + f];
    dout_gru[idx] = g;
    dout_fin[idx] = fin;
}

// ---------------------------------------------------------------------------
// Host side
// ---------------------------------------------------------------------------
namespace {
struct Ptrs {
    const float *sample, *A, *wq, *wk, *attn_bias, *attn_trans, *Wt, *bt_;
    const float *Wa1, *ba1, *Wa2, *ba2, *Wsrc, *bsrc, *Wtgt, *btgt;
    const float *Wgz, *bgz, *Wgr, *bgr, *Wgc, *bgc, *Wsh, *bsh, *Wl, *bl, *Wm, *bm;
    float *hidden, *nvs, *nvt, *Mcomb, *Ag, *comb, *comb2, *z, *P1, *P2;
    float *q, *kk, *th1, *th2, *tar32;
};

void gru_step(hipStream_t stream, const Ptrs& p, const float* graph, long gstride)
{
    dim3 bg(N / 64, 2, B);   // 256 blocks
    // hyper chain (M = Ag, C = 64)
    bmm3_kernel<0, false, false><<<bg, 256, 0, stream>>>(p.P1, p.hidden, p.hidden, p.Ag);
    bmm3_kernel<0, true,  false><<<bg, 256, 0, stream>>>(p.P2, p.hidden, p.P1, p.Ag);
    gsgt3_kernel<<<B * N / 32, 256, 0, stream>>>(
        p.hidden, p.P1, p.P2, p.Wa1, p.ba1, p.Wa2, p.ba2, graph, gstride,
        p.Wsrc, p.bsrc, p.Wtgt, p.btgt, p.nvs, p.nvt);
    adp3_kernel<<<dim3(N / 4, B), 512, 0, stream>>>(
        p.nvs, p.nvt, p.A, p.hidden, graph, gstride, p.Mcomb, p.comb);
    // rnn z/r chain (M = Mcomb, C = 66)
    bmm3_kernel<2, false, true><<<bg, 256, 0, stream>>>(p.P1, p.comb, p.comb, p.Mcomb);
    bmm3_kernel<2, true,  true><<<bg, 256, 0, stream>>>(p.P2, p.comb, p.P1, p.Mcomb);
    zr3_kernel<<<B * N / 16, 256, 0, stream>>>(
        p.comb, p.P1, p.P2, p.Wgz, p.bgz, p.Wgr, p.bgr, p.hidden, p.z, p.comb2);
    // rnn c chain
    bmm3_kernel<2, false, true><<<bg, 256, 0, stream>>>(p.P1, p.comb2, p.comb2, p.Mcomb);
    bmm3_kernel<2, true,  true><<<bg, 256, 0, stream>>>(p.P2, p.comb2, p.P1, p.Mcomb);
    cup3_kernel<<<B * N / 16, 256, 0, stream>>>(
        p.comb2, p.P1, p.P2, p.Wgc, p.bgc, p.z, p.hidden);
}
}  // namespace

extern "C" void kernel_launch(void* const* d_in, const int* in_sizes, int n_in,
                              void* d_out, int out_size, void* d_ws, size_t ws_size,
                              hipStream_t stream)
{
    (void)in_sizes; (void)n_in; (void)out_size; (void)ws_size;
    Ptrs p;
    p.sample = (const float*)d_in[0];
    p.A      = (const float*)d_in[1];
    p.wq     = (const float*)d_in[2];
    p.wk     = (const float*)d_in[3];
    p.attn_bias  = (const float*)d_in[4];
    p.attn_trans = (const float*)d_in[5];
    p.Wt  = (const float*)d_in[6];
    p.bt_ = (const float*)d_in[7];
    p.Wa1 = (const float*)d_in[8];
    p.ba1 = (const float*)d_in[9];
    p.Wa2 = (const float*)d_in[10];
    p.ba2 = (const float*)d_in[11];
    p.Wsrc = (const float*)d_in[12];
    p.bsrc = (const float*)d_in[13];
    p.Wtgt = (const float*)d_in[14];
    p.btgt = (const float*)d_in[15];
    p.Wgz = (const float*)d_in[16];
    p.bgz = (const float*)d_in[17];
    p.Wgr = (const float*)d_in[18];
    p.bgr = (const float*)d_in[19];
    p.Wgc = (const float*)d_in[20];
    p.bgc = (const float*)d_in[21];
    p.Wsh = (const float*)d_in[22];
    p.bsh = (const float*)d_in[23];
    p.Wl  = (const float*)d_in[24];
    p.bl  = (const float*)d_in[25];
    p.Wm  = (const float*)d_in[26];
    p.bm  = (const float*)d_in[27];

    float* ws = (float*)d_ws;
    size_t off = 0;
    auto alloc = [&](size_t nelem) { float* r = ws + off; off += nelem; return r; };
    p.hidden = alloc((size_t)B * N * H);
    p.nvs    = alloc((size_t)B * N * E);
    p.nvt    = alloc((size_t)B * N * E);
    p.Mcomb  = alloc((size_t)B * N * N);
    p.Ag     = alloc((size_t)N * N);
    p.comb   = alloc((size_t)B * N * CC);
    p.comb2  = alloc((size_t)B * N * CC);
    p.z      = alloc((size_t)B * N * H);
    p.P1     = alloc((size_t)2 * B * N * CC);   // partial pair (also used at stride B*N*H)
    p.P2     = alloc((size_t)2 * B * N * CC);
    p.q      = alloc((size_t)B * N * DA);
    p.kk     = alloc((size_t)B * 4 * N * DA);
    p.th1    = alloc((size_t)B * 4 * N * F);
    p.th2    = alloc((size_t)B * 4 * N * F);
    p.tar32  = alloc((size_t)B * N * TGN_OC);

    float* out = (float*)d_out;
    float* out_gat = out;
    float* out_gru = out + (size_t)B * N * F;
    float* out_fin = out + (size_t)2 * B * N * F;
    float* out_attn = out + (size_t)3 * B * N * F;

    hipMemsetAsync(p.hidden, 0, (size_t)B * N * H * sizeof(float), stream);
    scaleA_kernel<<<N * N / 256, 256, 0, stream>>>(p.A, p.Ag);

    for (int i = 0; i < 5; ++i) {
        const float* graph = p.sample + (size_t)(4 * i) * N * F;
        gru_step(stream, p, graph, (long)T * N * F);
    }

    qk_kernel<<<(B * N * DA + B * 4 * N * DA) / 256, 256, 0, stream>>>(
        p.sample, p.wq, p.wk, p.attn_bias, p.q, p.kk);
    scores_kernel<<<dim3(N, 4, B), 512, 0, stream>>>(p.q, p.kk, p.attn_trans, out_attn);

    const float* srcbase = p.sample + (size_t)(T - 4) * N * F;
    tgn_mm_kernel<<<dim3(N / 64, B * 4), 128, 0, stream>>>(
        p.A, out_attn, srcbase, (long)T * N * F, (long)N * F,
        srcbase, (long)T * N * F, (long)N * F, p.th1);
    tgn_mm_kernel<<<dim3(N / 64, B * 4), 128, 0, stream>>>(
        p.A, out_attn, p.th1, (long)4 * N * F, (long)N * F,
        srcbase, (long)T * N * F, (long)N * F, p.th2);
    tgn_out_kernel<<<(B * N * TGN_OC) / 256, 256, 0, stream>>>(
        p.sample, p.th1, p.th2, p.Wt, p.bt_, p.tar32);
    gat_kernel<<<(B * N * F) / 256, 256, 0, stream>>>(p.tar32, p.Wsh, p.bsh, out_gat);

    gru_step(stream, p, out_gat, (long)N * F);

    final_kernel<<<(B * N * F) / 256, 256, 0, stream>>>(
        p.hidden, p.tar32, p.Wl, p.bl, p.Wm, p.bm, out_gru, out_fin);
}